// Round 3
// baseline (692.400 us; speedup 1.0000x reference)
//
#include <hip/hip_runtime.h>
#include <stdint.h>

// FP32->FP64 bit-pulse converter, round 3.
//
// Wave tile = 8 rows (1024 B in / 2048 B out); each wave handles T=2 tiles.
//  Load:  lane k loads float4 #k of each tile -> fully coalesced 1024 B/instr,
//         two loads in flight per wave.
//  Pack:  4 ballots per tile -> all 256 tile bits in wave-uniform 64-bit masks.
//  Since ballots are wave-uniform, EVERY lane can rebuild ANY row's word.
//  Store: store s (s=0,1) writes chunk s*64+lane -> contiguous aligned 1024 B
//         per instruction (full cache lines, no partial-line writes).
//         Lane k rebuilds row s*4 + k/16 and emits nibble k%16 of that row.
//  Stores are nontemporal (output is write-once streaming, 512 MiB).

typedef float fvec4 __attribute__((ext_vector_type(4)));

__device__ __forceinline__ uint32_t spread4(uint32_t x) {
    // spread low 8 bits: bit i -> bit 4*i
    x &= 0xffu;
    x = (x | (x << 12)) & 0x000F000Fu;
    x = (x | (x << 6))  & 0x03030303u;
    x = (x | (x << 3))  & 0x11111111u;
    return x;
}

// Rebuild row r's 32-bit MSB-first pulse word from the tile ballots, convert
// FP32 bits -> FP64 bits, return bit-reversed FP64 word (bit j = out elem j).
__device__ __forceinline__ uint64_t convert_row(uint64_t b0, uint64_t b1,
                                                uint64_t b2, uint64_t b3,
                                                int r) {
    int sh = r * 8;
    uint32_t u = spread4((uint32_t)(b0 >> sh))
               | (spread4((uint32_t)(b1 >> sh)) << 1)
               | (spread4((uint32_t)(b2 >> sh)) << 2)
               | (spread4((uint32_t)(b3 >> sh)) << 3);
    uint32_t v = __brev(u);              // standard IEEE FP32 word
    uint32_t E = (v >> 23) & 0xffu;
    uint32_t M = v & 0x7fffffu;
    uint64_t S = (uint64_t)(v >> 31);
    uint64_t E64 = E ? (uint64_t)(E + 896u) : 0ull;   // rebias 1023-127
    uint64_t M64 = (uint64_t)M << 29;
    if (E == 255u) {                     // Inf / NaN
        E64 = 2047ull;
        M64 = M ? (1ull << 51) : 0ull;   // quiet NaN: mantissa MSB only
    }
    uint64_t v64 = (S << 63) | (E64 << 52) | M64;
    return __brevll(v64);
}

__global__ __launch_bounds__(256) void
fp32_to_fp64_pulse_kernel(const float4* __restrict__ in,
                          float4* __restrict__ out,
                          int nwaves) {
    int lane = threadIdx.x & 63;
    int w = (int)((blockIdx.x * blockDim.x + threadIdx.x) >> 6);
    if (w >= nwaves) return;  // wave-uniform (nwaves*64 == grid threads)

    // ---- 2 tiles per wave: both loads issued before any use ----
    size_t ibase = (size_t)w * 128 + lane;   // 2 tiles = 128 float4
    float4 g0 = in[ibase];
    float4 g1 = in[ibase + 64];

    int nsh = (lane & 15) * 4;               // nibble shift for this lane
    size_t obase = (size_t)w * 256 + lane;   // 2 tiles = 256 out chunks

#pragma unroll
    for (int t = 0; t < 2; ++t) {
        float4 g = t ? g1 : g0;
        // all 256 tile bits, wave-uniform: bit k of bc = elem 4k+c of tile
        uint64_t b0 = __ballot(g.x != 0.0f);
        uint64_t b1 = __ballot(g.y != 0.0f);
        uint64_t b2 = __ballot(g.z != 0.0f);
        uint64_t b3 = __ballot(g.w != 0.0f);

#pragma unroll
        for (int s = 0; s < 2; ++s) {
            // store s*64+lane covers row r = s*4 + lane/16, nibble lane%16
            int r = s * 4 + (lane >> 4);
            uint64_t rr = convert_row(b0, b1, b2, b3, r);
            uint32_t nib = (uint32_t)(rr >> nsh) & 0xfu;
            fvec4 f;
            f.x = (nib & 1u) ? 1.0f : 0.0f;
            f.y = (nib & 2u) ? 1.0f : 0.0f;
            f.z = (nib & 4u) ? 1.0f : 0.0f;
            f.w = (nib & 8u) ? 1.0f : 0.0f;
            __builtin_nontemporal_store(
                f, (fvec4*)&out[obase + (size_t)t * 128 + s * 64]);
        }
    }
}

extern "C" void kernel_launch(void* const* d_in, const int* in_sizes, int n_in,
                              void* d_out, int out_size, void* d_ws, size_t ws_size,
                              hipStream_t stream) {
    (void)n_in; (void)d_ws; (void)ws_size; (void)out_size;
    const float4* in = (const float4*)d_in[0];
    float4* out = (float4*)d_out;
    int nrows  = in_sizes[0] / 32;       // B = 2097152
    int nwaves = nrows / 16;             // 16 rows (2 tiles) per wave
    int threads = nwaves * 64;
    const int block = 256;
    int grid = (threads + block - 1) / block;
    fp32_to_fp64_pulse_kernel<<<grid, block, 0, stream>>>(in, out, nwaves);
}

// Round 5
// 676.193 us; speedup vs baseline: 1.0240x; 1.0240x over previous
//
#include <hip/hip_runtime.h>
#include <stdint.h>

// FP32->FP64 bit-pulse converter, round 4b (compile fix of round 4).
//
// Wave tile = 8 rows (1024 B in / 2048 B out); each wave handles T=4 tiles
// with ALL 4 loads issued before the first ballot (4 KiB reads in flight;
// tile t's ballot waits only vmcnt(3-t)).
//
//  Load:  lane k loads float4 #k of each tile (coalesced 1024 B/instr),
//         nontemporal (read-once, keep L2 for the write stream).
//  Pack:  4 ballots/tile -> 256 tile bits in wave-uniform 64-bit masks.
//  Convert: lane k rebuilds row lane/8's 32-bit word (nibble-spread of the
//         ballot bytes), does the integer FP32->FP64 bit conversion once.
//  Store: lane k writes chunks 2k, 2k+1 (stride-2 float4; the wave's two
//         stores jointly cover the contiguous 2048-B tile -> L2 merges).
//         Plain stores (nt stores regressed in round 3).

typedef float fvec4 __attribute__((ext_vector_type(4)));

__device__ __forceinline__ uint32_t spread4(uint32_t x) {
    // spread low 8 bits: bit i -> bit 4*i
    x &= 0xffu;
    x = (x | (x << 12)) & 0x000F000Fu;
    x = (x | (x << 6))  & 0x03030303u;
    x = (x | (x << 3))  & 0x11111111u;
    return x;
}

__device__ __forceinline__ void process_tile(fvec4 g, int sh, int nsh8,
                                             fvec4* __restrict__ tout) {
    // ---- pack all 256 tile bits: bit k of bc = (elem 4k+c of tile) != 0 ----
    uint64_t b0 = __ballot(g.x != 0.0f);
    uint64_t b1 = __ballot(g.y != 0.0f);
    uint64_t b2 = __ballot(g.z != 0.0f);
    uint64_t b3 = __ballot(g.w != 0.0f);

    // ---- rebuild this lane's row word (row = lane/8, MSB-first) ----
    uint32_t u = spread4((uint32_t)(b0 >> sh))
               | (spread4((uint32_t)(b1 >> sh)) << 1)
               | (spread4((uint32_t)(b2 >> sh)) << 2)
               | (spread4((uint32_t)(b3 >> sh)) << 3);

    // ---- FP32 -> FP64 bit conversion ----
    uint32_t v = __brev(u);              // standard IEEE FP32 word
    uint32_t E = (v >> 23) & 0xffu;
    uint32_t M = v & 0x7fffffu;
    uint64_t S = (uint64_t)(v >> 31);
    uint64_t E64 = E ? (uint64_t)(E + 896u) : 0ull;  // rebias 1023-127
    uint64_t M64 = (uint64_t)M << 29;
    if (E == 255u) {                     // Inf / NaN
        E64 = 2047ull;
        M64 = M ? (1ull << 51) : 0ull;   // quiet NaN: mantissa MSB only
    }
    uint64_t v64 = (S << 63) | (E64 << 52) | M64;
    uint64_t rr  = __brevll(v64);        // bit j == output element j of row

    // ---- stores: this lane's byte of rr -> chunks 2*lane, 2*lane+1 ----
    uint32_t ob = (uint32_t)(rr >> nsh8) & 0xffu;
    fvec4 f1, f2;
    f1.x = (ob & 1u)   ? 1.0f : 0.0f;
    f1.y = (ob & 2u)   ? 1.0f : 0.0f;
    f1.z = (ob & 4u)   ? 1.0f : 0.0f;
    f1.w = (ob & 8u)   ? 1.0f : 0.0f;
    f2.x = (ob & 16u)  ? 1.0f : 0.0f;
    f2.y = (ob & 32u)  ? 1.0f : 0.0f;
    f2.z = (ob & 64u)  ? 1.0f : 0.0f;
    f2.w = (ob & 128u) ? 1.0f : 0.0f;
    tout[0] = f1;
    tout[1] = f2;
}

__global__ __launch_bounds__(256) void
fp32_to_fp64_pulse_kernel(const fvec4* __restrict__ in,
                          fvec4* __restrict__ out) {
    int lane = threadIdx.x & 63;
    int w = (int)((blockIdx.x * blockDim.x + threadIdx.x) >> 6);

    int sh   = lane & 56;        // 8 * (lane/8): byte of ballots for my row
    int nsh8 = (lane & 7) * 8;   // my byte within the row's 64 output bits

    // ---- 4 tiles per wave: all loads in flight before first ballot ----
    const fvec4* ib = in + (size_t)w * 256 + lane;   // 4 tiles = 256 fvec4
    fvec4 g0 = __builtin_nontemporal_load(ib);
    fvec4 g1 = __builtin_nontemporal_load(ib + 64);
    fvec4 g2 = __builtin_nontemporal_load(ib + 128);
    fvec4 g3 = __builtin_nontemporal_load(ib + 192);

    fvec4* ob = out + (size_t)w * 512 + ((size_t)lane << 1);  // 4x128 chunks
    process_tile(g0, sh, nsh8, ob);
    process_tile(g1, sh, nsh8, ob + 128);
    process_tile(g2, sh, nsh8, ob + 256);
    process_tile(g3, sh, nsh8, ob + 384);
}

extern "C" void kernel_launch(void* const* d_in, const int* in_sizes, int n_in,
                              void* d_out, int out_size, void* d_ws, size_t ws_size,
                              hipStream_t stream) {
    (void)n_in; (void)d_ws; (void)ws_size; (void)out_size;
    const fvec4* in = (const fvec4*)d_in[0];
    fvec4* out = (fvec4*)d_out;
    int nrows  = in_sizes[0] / 32;       // B = 2097152
    int nwaves = nrows / 32;             // 32 rows (4 tiles) per wave -> 65536
    int threads = nwaves * 64;
    const int block = 256;
    int grid = threads / block;          // exact: B divisible by 32*4
    fp32_to_fp64_pulse_kernel<<<grid, block, 0, stream>>>(in, out);
}

// Round 6
// 661.827 us; speedup vs baseline: 1.0462x; 1.0217x over previous
//
#include <hip/hip_runtime.h>
#include <stdint.h>

// FP32->FP64 bit-pulse converter, round 6.
//
// Wave tile = 8 rows (1024 B in / 2048 B out), 1 tile per wave (R2 config,
// which is the best so far at 674 us). Single change vs R2: STORE PATTERN.
//
// R2 stored stride-2 float4 (each 32-B L2 sector half-written by two
// different store instructions -> possible read-for-ownership on the output
// stream). Here each lane still converts ONE row (row = lane/8), then two
// 64-bit ds_bpermute shuffles redistribute the converted words so that each
// of the two store instructions writes a CONTIGUOUS aligned 1024-B span
// (every 32-B sector fully covered by one instruction).
//
//   store s (s=0,1): lane k writes chunk s*64+k  (chunk = float4 = 4 elems)
//   chunk c belongs to row c/16, nibble c%16 of that row's 64 output bits.
//   lane k needs row s*4 + k/16, held by lane 32*s + 8*(k/16).

typedef float fvec4 __attribute__((ext_vector_type(4)));

__device__ __forceinline__ uint32_t spread4(uint32_t x) {
    // spread low 8 bits: bit i -> bit 4*i
    x &= 0xffu;
    x = (x | (x << 12)) & 0x000F000Fu;
    x = (x | (x << 6))  & 0x03030303u;
    x = (x | (x << 3))  & 0x11111111u;
    return x;
}

__device__ __forceinline__ uint64_t shfl64(uint64_t x, int srcLane) {
    int addr = srcLane << 2;  // ds_bpermute index is lane*4 bytes
    uint32_t lo = (uint32_t)__builtin_amdgcn_ds_bpermute(addr, (int)(uint32_t)x);
    uint32_t hi = (uint32_t)__builtin_amdgcn_ds_bpermute(addr, (int)(uint32_t)(x >> 32));
    return ((uint64_t)hi << 32) | lo;
}

__device__ __forceinline__ fvec4 nib2f(uint32_t nib) {
    fvec4 f;
    f.x = (nib & 1u) ? 1.0f : 0.0f;
    f.y = (nib & 2u) ? 1.0f : 0.0f;
    f.z = (nib & 4u) ? 1.0f : 0.0f;
    f.w = (nib & 8u) ? 1.0f : 0.0f;
    return f;
}

__global__ __launch_bounds__(256) void
fp32_to_fp64_pulse_kernel(const fvec4* __restrict__ in,
                          fvec4* __restrict__ out) {
    int lane = threadIdx.x & 63;
    int w = (int)((blockIdx.x * blockDim.x + threadIdx.x) >> 6);

    // ---- coalesced load: 8 rows = 64 float4 (nontemporal, read-once) ----
    fvec4 g = __builtin_nontemporal_load(in + (size_t)w * 64 + lane);

    // ---- pack all 256 tile bits: bit k of bc = (elem 4k+c of tile) != 0 ----
    uint64_t b0 = __ballot(g.x != 0.0f);
    uint64_t b1 = __ballot(g.y != 0.0f);
    uint64_t b2 = __ballot(g.z != 0.0f);
    uint64_t b3 = __ballot(g.w != 0.0f);

    // ---- rebuild this lane's row word (row = lane/8, MSB-first) ----
    int sh = lane & 56;  // 8 * (lane/8)
    uint32_t u = spread4((uint32_t)(b0 >> sh))
               | (spread4((uint32_t)(b1 >> sh)) << 1)
               | (spread4((uint32_t)(b2 >> sh)) << 2)
               | (spread4((uint32_t)(b3 >> sh)) << 3);

    // ---- FP32 -> FP64 bit conversion (once per lane) ----
    uint32_t v = __brev(u);              // standard IEEE FP32 word
    uint32_t E = (v >> 23) & 0xffu;
    uint32_t M = v & 0x7fffffu;
    uint64_t S = (uint64_t)(v >> 31);
    uint64_t E64 = E ? (uint64_t)(E + 896u) : 0ull;  // rebias 1023-127
    uint64_t M64 = (uint64_t)M << 29;
    if (E == 255u) {                     // Inf / NaN
        E64 = 2047ull;
        M64 = M ? (1ull << 51) : 0ull;   // quiet NaN: mantissa MSB only
    }
    uint64_t v64 = (S << 63) | (E64 << 52) | M64;
    uint64_t rr  = __brevll(v64);        // bit j == output element j of row

    // ---- redistribute rows so each store is a contiguous 1024-B span ----
    int src0 = (lane & 48) >> 1;         // 8 * (lane/16): holder of row lane/16
    uint64_t r0 = shfl64(rr, src0);      // row lane/16      (chunks 0..63)
    uint64_t r1 = shfl64(rr, src0 + 32); // row 4 + lane/16  (chunks 64..127)

    int nsh = (lane & 15) * 4;           // my nibble within the row
    fvec4 f0 = nib2f((uint32_t)(r0 >> nsh) & 0xfu);
    fvec4 f1 = nib2f((uint32_t)(r1 >> nsh) & 0xfu);

    fvec4* ob = out + (size_t)w * 128 + lane;
    ob[0]  = f0;     // chunks 0..63   : contiguous 1024 B
    ob[64] = f1;     // chunks 64..127 : contiguous 1024 B
}

extern "C" void kernel_launch(void* const* d_in, const int* in_sizes, int n_in,
                              void* d_out, int out_size, void* d_ws, size_t ws_size,
                              hipStream_t stream) {
    (void)n_in; (void)d_ws; (void)ws_size; (void)out_size;
    const fvec4* in = (const fvec4*)d_in[0];
    fvec4* out = (fvec4*)d_out;
    int nrows  = in_sizes[0] / 32;       // B = 2097152
    int nwaves = nrows / 8;              // 8 rows per wave
    int threads = nwaves * 64;
    const int block = 256;
    int grid = threads / block;          // exact: B divisible by 32
    fp32_to_fp64_pulse_kernel<<<grid, block, 0, stream>>>(in, out);
}

// Round 7
// 657.436 us; speedup vs baseline: 1.0532x; 1.0067x over previous
//
#include <hip/hip_runtime.h>
#include <stdint.h>

// FP32->FP64 bit-pulse converter, round 7.
// EXACTLY round 6 (best: 662 us) with ONE change: the two contiguous
// 1024-B-span stores are nontemporal (output is write-once streaming,
// 512 MiB; skip L2 allocation so the read stream keeps the cache).
//
// Wave tile = 8 rows (1024 B in / 2048 B out), 1 tile per wave.
//  Load:  lane k loads float4 #k (coalesced, nontemporal).
//  Pack:  4 ballots -> 256 tile bits in wave-uniform 64-bit masks.
//  Convert: lane k rebuilds row lane/8's word, integer FP32->FP64 bits.
//  Shuffle: two 64-bit ds_bpermute redistributions so each store
//           instruction writes a contiguous aligned 1024-B span.

typedef float fvec4 __attribute__((ext_vector_type(4)));

__device__ __forceinline__ uint32_t spread4(uint32_t x) {
    // spread low 8 bits: bit i -> bit 4*i
    x &= 0xffu;
    x = (x | (x << 12)) & 0x000F000Fu;
    x = (x | (x << 6))  & 0x03030303u;
    x = (x | (x << 3))  & 0x11111111u;
    return x;
}

__device__ __forceinline__ uint64_t shfl64(uint64_t x, int srcLane) {
    int addr = srcLane << 2;  // ds_bpermute index is lane*4 bytes
    uint32_t lo = (uint32_t)__builtin_amdgcn_ds_bpermute(addr, (int)(uint32_t)x);
    uint32_t hi = (uint32_t)__builtin_amdgcn_ds_bpermute(addr, (int)(uint32_t)(x >> 32));
    return ((uint64_t)hi << 32) | lo;
}

__device__ __forceinline__ fvec4 nib2f(uint32_t nib) {
    fvec4 f;
    f.x = (nib & 1u) ? 1.0f : 0.0f;
    f.y = (nib & 2u) ? 1.0f : 0.0f;
    f.z = (nib & 4u) ? 1.0f : 0.0f;
    f.w = (nib & 8u) ? 1.0f : 0.0f;
    return f;
}

__global__ __launch_bounds__(256) void
fp32_to_fp64_pulse_kernel(const fvec4* __restrict__ in,
                          fvec4* __restrict__ out) {
    int lane = threadIdx.x & 63;
    int w = (int)((blockIdx.x * blockDim.x + threadIdx.x) >> 6);

    // ---- coalesced load: 8 rows = 64 float4 (nontemporal, read-once) ----
    fvec4 g = __builtin_nontemporal_load(in + (size_t)w * 64 + lane);

    // ---- pack all 256 tile bits: bit k of bc = (elem 4k+c of tile) != 0 ----
    uint64_t b0 = __ballot(g.x != 0.0f);
    uint64_t b1 = __ballot(g.y != 0.0f);
    uint64_t b2 = __ballot(g.z != 0.0f);
    uint64_t b3 = __ballot(g.w != 0.0f);

    // ---- rebuild this lane's row word (row = lane/8, MSB-first) ----
    int sh = lane & 56;  // 8 * (lane/8)
    uint32_t u = spread4((uint32_t)(b0 >> sh))
               | (spread4((uint32_t)(b1 >> sh)) << 1)
               | (spread4((uint32_t)(b2 >> sh)) << 2)
               | (spread4((uint32_t)(b3 >> sh)) << 3);

    // ---- FP32 -> FP64 bit conversion (once per lane) ----
    uint32_t v = __brev(u);              // standard IEEE FP32 word
    uint32_t E = (v >> 23) & 0xffu;
    uint32_t M = v & 0x7fffffu;
    uint64_t S = (uint64_t)(v >> 31);
    uint64_t E64 = E ? (uint64_t)(E + 896u) : 0ull;  // rebias 1023-127
    uint64_t M64 = (uint64_t)M << 29;
    if (E == 255u) {                     // Inf / NaN
        E64 = 2047ull;
        M64 = M ? (1ull << 51) : 0ull;   // quiet NaN: mantissa MSB only
    }
    uint64_t v64 = (S << 63) | (E64 << 52) | M64;
    uint64_t rr  = __brevll(v64);        // bit j == output element j of row

    // ---- redistribute rows so each store is a contiguous 1024-B span ----
    int src0 = (lane & 48) >> 1;         // 8 * (lane/16): holder of row lane/16
    uint64_t r0 = shfl64(rr, src0);      // row lane/16      (chunks 0..63)
    uint64_t r1 = shfl64(rr, src0 + 32); // row 4 + lane/16  (chunks 64..127)

    int nsh = (lane & 15) * 4;           // my nibble within the row
    fvec4 f0 = nib2f((uint32_t)(r0 >> nsh) & 0xfu);
    fvec4 f1 = nib2f((uint32_t)(r1 >> nsh) & 0xfu);

    fvec4* ob = out + (size_t)w * 128 + lane;
    __builtin_nontemporal_store(f0, ob);       // chunks 0..63
    __builtin_nontemporal_store(f1, ob + 64);  // chunks 64..127
}

extern "C" void kernel_launch(void* const* d_in, const int* in_sizes, int n_in,
                              void* d_out, int out_size, void* d_ws, size_t ws_size,
                              hipStream_t stream) {
    (void)n_in; (void)d_ws; (void)ws_size; (void)out_size;
    const fvec4* in = (const fvec4*)d_in[0];
    fvec4* out = (fvec4*)d_out;
    int nrows  = in_sizes[0] / 32;       // B = 2097152
    int nwaves = nrows / 8;              // 8 rows per wave
    int threads = nwaves * 64;
    const int block = 256;
    int grid = threads / block;          // exact: B divisible by 32
    fp32_to_fp64_pulse_kernel<<<grid, block, 0, stream>>>(in, out);
}